// Round 18
// baseline (414.740 us; speedup 1.0000x reference)
//
#include <hip/hip_runtime.h>
#include <hip/hip_bf16.h>

#define THREADS 512
#define NBLK 256
#define NGRP 32
#define GROWS 64
#define IMGU (173*512)                       // ushorts per member image (173 KB)
#define H1OFF  (8*IMGU*2)                    // 1,417,216 B
#define H1SZ   (NGRP*64*1024)                // 2 MB   (32 groups x 64 frags)
#define KPOFF  (H1OFF + H1SZ)
#define KPSZ   (NGRP*8*4096)                 // 1 MB   (8 members x [64][32] bf16)
#define CNTOFF (KPOFF + KPSZ)                // 32 groups x 256 B (padded: no false sharing)

typedef float f32x4 __attribute__((ext_vector_type(4)));
typedef int   i32x2 __attribute__((ext_vector_type(2)));
typedef __bf16 bf16x8 __attribute__((ext_vector_type(8)));
typedef unsigned short u16x4 __attribute__((ext_vector_type(4)));

static __device__ __forceinline__ unsigned short f2bfu(float f) {
    __hip_bfloat16 h = __float2bfloat16(f);
    unsigned short u; __builtin_memcpy(&u, &h, 2); return u;
}
static __device__ __forceinline__ float bfu2f(unsigned short u) {
    unsigned int x = ((unsigned int)u) << 16;
    float f; __builtin_memcpy(&f, &x, 4); return f;
}

#define MFMA(a, b, c) __builtin_amdgcn_mfma_f32_16x16x32_bf16((a), (b), (c), 0, 0, 0)
#define BC(x)  __builtin_bit_cast(bf16x8, (x))
#define BC2(x) __builtin_bit_cast(i32x2, (x))
#define BCU(x) __builtin_bit_cast(u16x4, (x))

// agent-scope (sc1) communication ops: write-through to MALL / read MALL, bypass L1+L2.
#define LOADG(dst, addr) \
    asm volatile("global_load_dwordx4 %0, %1, off sc1" : "=v"(dst) : "v"(addr))
#define LOADC2(dst, addr) \
    asm volatile("global_load_dwordx2 %0, %1, off sc1" : "=v"(dst) : "v"(addr))
#define STOREC8(addr, val) \
    asm volatile("global_store_dwordx2 %0, %1, off sc1" :: "v"(addr), "v"(val) : "memory")
#define SBAR() __builtin_amdgcn_sched_barrier(0)

__global__ void zero_cnt(unsigned* c) { c[blockIdx.x * 256 + threadIdx.x] = 0u; }

// Per-member weight image: 128 W2 frags | 32 W1c frags | 8 W1a frags | 4 W3 frags | vec block.
// Frag element: lane l, j -> W[k = kt*32 + (l>>4)*8 + j][n = ntg*16 + (l&15)]
__global__ void pack_members(const float* __restrict__ W1, const float* __restrict__ W2,
                             const float* __restrict__ W3, const float* __restrict__ b1,
                             const float* __restrict__ b2, const float* __restrict__ b3,
                             unsigned short* __restrict__ dst) {
    int b = blockIdx.x, m = b / 173, fi = b % 173, lane = threadIdx.x;
    unsigned short* base = dst + (size_t)m * IMGU;
    if (fi == 172) {   // vec block: w1tA|w1tB|b1A|b1B|b2A|b2B (64 u16 each) + b3 (32 f32)
        unsigned short* vb = base + 172 * 512;
        for (int i = lane; i < 384; i += 64) {
            int region = i >> 6, o = i & 63;
            int cA = m * 64 + o, cB = 512 + m * 64 + o;
            float v = 0.f;
            if (region == 0) v = W1[32 * 1024 + cA];
            else if (region == 1) v = W1[32 * 1024 + cB];
            else if (region == 2) v = b1[cA];
            else if (region == 3) v = b1[cB];
            else if (region == 4) v = b2[cA];
            else                  v = b2[cB];
            vb[i] = f2bfu(v);
        }
        if (lane < 32) ((float*)(vb + 384))[lane] = b3[lane];
        return;
    }
    const float* W; int kbase, n, N;
    if (fi < 128) {        // W2 slice frags: idx = kt*8 + ntl
        int kt = fi >> 3, ntl = fi & 7;
        int ntg = (ntl < 4) ? (m * 4 + ntl) : (32 + m * 4 + (ntl - 4));
        W = W2; N = 1024; kbase = kt * 32; n = ntg * 16 + (lane & 15);
    } else if (fi < 160) { // W1c frags: idx = ktc*8 + ntl (ctx rows 33..160)
        int fj = fi - 128, ktc = fj >> 3, ntl = fj & 7;
        int ntg = (ntl < 4) ? (m * 4 + ntl) : (32 + m * 4 + (ntl - 4));
        W = W1 + 33 * 1024; N = 1024; kbase = ktc * 32; n = ntg * 16 + (lane & 15);
    } else if (fi < 168) { // W1a frags: idx = ntl (theta rows 0..31)
        int ntl = fi - 160;
        int ntg = (ntl < 4) ? (m * 4 + ntl) : (32 + m * 4 + (ntl - 4));
        W = W1; N = 1024; kbase = 0; n = ntg * 16 + (lane & 15);
    } else {               // W3 frags: idx = ktl*2 + nt3 (K-slice rows m*64..)
        int fj = fi - 168, ktl = fj >> 1, nt3 = fj & 1;
        W = W3; N = 32; kbase = m * 64 + ktl * 32; n = nt3 * 16 + (lane & 15);
    }
    kbase += (lane >> 4) * 8;
    union { unsigned short s[8]; int4 v; } u;
#pragma unroll
    for (int j = 0; j < 8; j++) u.s[j] = f2bfu(W[(size_t)(kbase + j) * N + n]);
    *reinterpret_cast<int4*>(base + (size_t)fi * 512 + lane * 8) = u.v;
}

// r15 protocol: relaxed add + relaxed poll, no fences (comm data is sc1/MALL-coherent).
static __device__ __forceinline__ void group_sync(unsigned* c, unsigned tgt) {
    __syncthreads();   // per-wave vmcnt(0) drain -> all waves' sc1 stores at MALL
    if (threadIdx.x == 0) {
        __hip_atomic_fetch_add(c, 1u, __ATOMIC_RELAXED, __HIP_MEMORY_SCOPE_AGENT);
        int gd = 0;
        while (__hip_atomic_load(c, __ATOMIC_RELAXED, __HIP_MEMORY_SCOPE_AGENT) < tgt) {
            __builtin_amdgcn_s_sleep(2);
            if (++gd > (1 << 22)) break;   // safety valve: terminate, never hang
        }
    }
    __syncthreads();
}

__global__ __launch_bounds__(THREADS, 2)
void ccnf_main(const float* __restrict__ theta0,
               const float* __restrict__ ctx,
               char* __restrict__ wsb,
               const int* __restrict__ nsteps_p,
               float* __restrict__ out)
{
    // LDS: W2 128K | cxt1 16K | h2 8K (scratch + final) | x 4K = 156 KB (1 block/CU)
    __shared__ __align__(16) unsigned short w2s[128 * 512];
    __shared__ __align__(16) unsigned short cxts[32 * 64 * 4];  // [z4][row][4] (conflict-free)
    __shared__ __align__(16) unsigned short h2s[8 * 512];       // scratch passes, then frag(ktl*4+rt)
    __shared__ __align__(16) unsigned short als[2048];          // x frags [d>>3][row][d&7]

    const int tid = threadIdx.x;
    const int lane = tid & 63, wv = tid >> 6;
    const int rt = wv & 3, nh = wv >> 2;            // wave -> (rowtile, n-half / K-half)
    const int r16 = lane & 15, wq = lane >> 4, rb4 = wq * 4;
    const int row = rt * 16 + r16;
    const int g = blockIdx.x & 31, m = blockIdx.x >> 5;
    const int row0 = g * GROWS;

    const unsigned short* img = (const unsigned short*)wsb + (size_t)m * IMGU;
    unsigned short* h1u = (unsigned short*)(wsb + H1OFF) + (size_t)g * (64 * 512);
    unsigned short* kpu = (unsigned short*)(wsb + KPOFF) + (size_t)g * (8 * 2048);
    unsigned* cnt = (unsigned*)(wsb + CNTOFF) + g * 64;   // 256 B per group: private line
    const char* h1lane = (const char*)h1u + lane * 16;

    // ---- resident VGPR constants ----
    bf16x8 w1aA[2], w1aB[2], w3f[2];
    u16x4 w1tA[2], w1tB[2], b1A[2], b1B[2];
#pragma unroll
    for (int k = 0; k < 2; ++k) {
        w1aA[k] = *(const bf16x8*)(img + (160 + 2 * nh + k) * 512 + lane * 8);
        w1aB[k] = *(const bf16x8*)(img + (164 + 2 * nh + k) * 512 + lane * 8);
        w3f[k]  = *(const bf16x8*)(img + (168 + k * 2 + nh) * 512 + lane * 8);
        int cl = (2 * nh + k) * 16 + rb4;
        const unsigned short* vu = img + 172 * 512;
        w1tA[k] = *(const u16x4*)(vu + cl);       w1tB[k] = *(const u16x4*)(vu + 64 + cl);
        b1A[k]  = *(const u16x4*)(vu + 128 + cl); b1B[k]  = *(const u16x4*)(vu + 192 + cl);
    }
    // L2 GLU biases for ALL 4 member n-tiles (kh-split waves each cover all ntl)
    u16x4 b2Ar[4], b2Br[4];
#pragma unroll
    for (int t = 0; t < 4; ++t) {
        const unsigned short* vu = img + 172 * 512;
        b2Ar[t] = *(const u16x4*)(vu + 256 + t * 16 + rb4);
        b2Br[t] = *(const u16x4*)(vu + 320 + t * 16 + rb4);
    }
    const int rowc = tid >> 3, db = (tid & 7) * 4;
    const float4 b3v = *(const float4*)((const float*)(img + 172 * 512 + 384) + db);

    // ---- prologue: W1c -> LDS (transient), ctx staging, theta ----
#pragma unroll
    for (int q = 0; q < 4; ++q) {   // 32 W1c frags -> w2s[0..32)
        int idx = wv * 4 + q;
        __builtin_amdgcn_global_load_lds(
            (const __attribute__((address_space(1))) void*)((const char*)img + (size_t)(128 + idx) * 1024 + lane * 16),
            (__attribute__((address_space(3))) void*)(w2s + idx * 512), 16, 0, 0);
    }
    {   // ctx [64 rows][128] fp32 -> staging frags at w2s[32*512..]
        const float* cp = ctx + (size_t)(row0 + rowc) * 128 + (tid & 7) * 16;
        float4 v0 = ((const float4*)cp)[0], v1 = ((const float4*)cp)[1];
        float4 v2 = ((const float4*)cp)[2], v3 = ((const float4*)cp)[3];
        int c0 = (tid & 7) * 16;
        unsigned short* sb = w2s + 16384 + (c0 >> 5) * 2048 + ((c0 & 31) >> 3) * 512 + rowc * 8;
        u16x4 o;
        o[0]=f2bfu(v0.x); o[1]=f2bfu(v0.y); o[2]=f2bfu(v0.z); o[3]=f2bfu(v0.w); *(u16x4*)(sb) = o;
        o[0]=f2bfu(v1.x); o[1]=f2bfu(v1.y); o[2]=f2bfu(v1.z); o[3]=f2bfu(v1.w); *(u16x4*)(sb + 4) = o;
        o[0]=f2bfu(v2.x); o[1]=f2bfu(v2.y); o[2]=f2bfu(v2.z); o[3]=f2bfu(v2.w); *(u16x4*)(sb + 512) = o;
        o[0]=f2bfu(v3.x); o[1]=f2bfu(v3.y); o[2]=f2bfu(v3.z); o[3]=f2bfu(v3.w); *(u16x4*)(sb + 516) = o;
    }
    float th[4], acck[4];
    {
        float4 t0 = *(const float4*)(theta0 + (size_t)(row0 + rowc) * 32 + db);
        th[0]=t0.x; th[1]=t0.y; th[2]=t0.z; th[3]=t0.w;
        acck[0]=acck[1]=acck[2]=acck[3]=0.f;
        u16x4 xo; xo[0]=f2bfu(t0.x); xo[1]=f2bfu(t0.y); xo[2]=f2bfu(t0.z); xo[3]=f2bfu(t0.w);
        *(u16x4*)(als + (db >> 3) * 512 + rowc * 8 + (db & 7)) = xo;
    }
    const int nst = nsteps_p[0];
    const float dt = 1.0f / (float)nst;
    __syncthreads();

    // ---- cxt1 = ctx @ W1c-slice; store z4-major [z4][row][4] ----
#pragma unroll
    for (int ab = 0; ab < 2; ++ab)
#pragma unroll
        for (int k = 0; k < 2; ++k) {
            int ntl = ab * 4 + 2 * nh + k;
            f32x4 a = {0.f, 0.f, 0.f, 0.f};
#pragma unroll
            for (int ktc = 0; ktc < 4; ++ktc) {
                bf16x8 cf = *(const bf16x8*)(w2s + 16384 + ktc * 2048 + wq * 512 + row * 8);
                bf16x8 wf = *(const bf16x8*)(w2s + (ktc * 8 + ntl) * 512 + lane * 8);
                a = MFMA(wf, cf, a);
            }
            u16x4 o;
#pragma unroll
            for (int i = 0; i < 4; ++i) o[i] = f2bfu(a[i]);
            int z4 = ab * 16 + (2 * nh + k) * 4 + wq;
            *(u16x4*)(cxts + (z4 * 64 + row) * 4) = o;
        }
    __syncthreads();   // W1c/ctx staging consumed; w2s free

    // ---- W2 slice -> LDS (resident) ----
#pragma unroll
    for (int q = 0; q < 16; ++q) {
        int idx = wv * 16 + q;
        __builtin_amdgcn_global_load_lds(
            (const __attribute__((address_space(1))) void*)((const char*)img + (size_t)idx * 1024 + lane * 16),
            (__attribute__((address_space(3))) void*)(w2s + idx * 512), 16, 0, 0);
    }
    __syncthreads();

    // ---- main loop: 4*nst evals, 2 group-syncs each ----
    const int ne = 4 * nst;
    for (int e = 0; e < ne; ++e) {
        const int s = e & 3;
        const float tt = (float)(e >> 2) * dt + ((s == 0) ? 0.f : (s == 3) ? dt : 0.5f * dt);

        // === L1: z-slice = x@W1a + cxt1 + b1 + t*w1t; GLU -> global h1 frag(2m+nh, rt) ===
        {
            bf16x8 xf = *(const bf16x8*)(als + wq * 512 + row * 8);
            unsigned short* fb = h1u + ((2 * m + nh) * 4 + rt) * 512;
#pragma unroll
            for (int k = 0; k < 2; ++k) {
                f32x4 z = {0.f, 0.f, 0.f, 0.f};
                f32x4 zA = MFMA(w1aA[k], xf, z);
                f32x4 zB = MFMA(w1aB[k], xf, z);
                int zA4 = (2 * nh + k) * 4 + wq, zB4 = 16 + zA4;
                u16x4 cA = *(const u16x4*)(cxts + (zA4 * 64 + row) * 4);
                u16x4 cB = *(const u16x4*)(cxts + (zB4 * 64 + row) * 4);
                u16x4 o;
#pragma unroll
                for (int i = 0; i < 4; ++i) {
                    float va = zA[i] + bfu2f(cA[i]) + bfu2f(b1A[k][i]) + tt * bfu2f(w1tA[k][i]);
                    float vb = zB[i] + bfu2f(cB[i]) + bfu2f(b1B[k][i]) + tt * bfu2f(w1tB[k][i]);
                    o[i] = f2bfu(va * (1.f / (1.f + __expf(-vb))));
                }
                STOREC8(fb + (k * 2 + (wq >> 1)) * 128 + r16 * 8 + (wq & 1) * 4, BC2(o));
            }
        }
        group_sync(&cnt[0], 8u * (unsigned)(e + 1));   // h1 ready group-wide

        // === L2: kh-split (kh = nh). Wave loads 8 UNIQUE h1 frags (64 KB/block, halved
        //     MALL traffic), computes all 8 member ntiles over its K-half; two-pass bf16
        //     partial reduction through h2s scratch; kh=0 waves finalize GLU -> h2s. ===
        {
            f32x4 accA[4], accB[4];
#pragma unroll
            for (int t = 0; t < 4; ++t) { f32x4 z = {0.f,0.f,0.f,0.f}; accA[t] = z; accB[t] = z; }
            f32x4 gb[8];
#pragma unroll
            for (int q = 0; q < 8; ++q)
                LOADG(gb[q], h1lane + ((nh * 8 + q) * 4 + rt) * 1024);
#pragma unroll
            for (int j = 0; j < 8; ++j) {
                if (j == 0)      asm volatile("s_waitcnt vmcnt(7)" ::: "memory");
                else if (j == 1) asm volatile("s_waitcnt vmcnt(6)" ::: "memory");
                else if (j == 2) asm volatile("s_waitcnt vmcnt(5)" ::: "memory");
                else if (j == 3) asm volatile("s_waitcnt vmcnt(4)" ::: "memory");
                else if (j == 4) asm volatile("s_waitcnt vmcnt(3)" ::: "memory");
                else if (j == 5) asm volatile("s_waitcnt vmcnt(2)" ::: "memory");
                else if (j == 6) asm volatile("s_waitcnt vmcnt(1)" ::: "memory");
                else             asm volatile("s_waitcnt vmcnt(0)" ::: "memory");
                SBAR();
                const int kt = nh * 8 + j;
                bf16x8 hf = BC(gb[j]);
#pragma unroll
                for (int t = 0; t < 4; ++t) {
                    accA[t] = MFMA(*(const bf16x8*)(w2s + (kt * 8 + t) * 512 + lane * 8), hf, accA[t]);
                    accB[t] = MFMA(*(const bf16x8*)(w2s + (kt * 8 + 4 + t) * 512 + lane * 8), hf, accB[t]);
                }
            }
            // pass A: kh=1 publishes accA partials (bf16) through h2s scratch
            if (nh == 1) {
#pragma unroll
                for (int t = 0; t < 4; ++t) {
                    u16x4 o;
#pragma unroll
                    for (int i = 0; i < 4; ++i) o[i] = f2bfu(accA[t][i]);
                    *(u16x4*)(h2s + ((rt * 4 + t) * 64 + lane) * 4) = o;
                }
            }
            __syncthreads();
            if (nh == 0) {
#pragma unroll
                for (int t = 0; t < 4; ++t) {
                    u16x4 p = *(const u16x4*)(h2s + ((rt * 4 + t) * 64 + lane) * 4);
#pragma unroll
                    for (int i = 0; i < 4; ++i) accA[t][i] += bfu2f(p[i]);
                }
            }
            __syncthreads();   // scratch consumed
            // pass B: kh=1 publishes accB partials
            if (nh == 1) {
#pragma unroll
                for (int t = 0; t < 4; ++t) {
                    u16x4 o;
#pragma unroll
                    for (int i = 0; i < 4; ++i) o[i] = f2bfu(accB[t][i]);
                    *(u16x4*)(h2s + ((rt * 4 + t) * 64 + lane) * 4) = o;
                }
            }
            __syncthreads();
            u16x4 hres[4];
            if (nh == 0) {
#pragma unroll
                for (int t = 0; t < 4; ++t) {
                    u16x4 p = *(const u16x4*)(h2s + ((rt * 4 + t) * 64 + lane) * 4);
#pragma unroll
                    for (int i = 0; i < 4; ++i) {
                        float va = accA[t][i] + bfu2f(b2Ar[t][i]);
                        float vb = accB[t][i] + bfu2f(p[i]) + bfu2f(b2Br[t][i]);
                        hres[t][i] = f2bfu(va * (1.f / (1.f + __expf(-vb))));
                    }
                }
            }
            __syncthreads();   // all scratch reads done; h2s free for final layout
            if (nh == 0) {
#pragma unroll
                for (int t = 0; t < 4; ++t)
                    *(u16x4*)(h2s + ((t >> 1) * 4 + rt) * 512
                              + (((t & 1) * 2 + (wq >> 1)) * 16 + r16) * 8 + (wq & 1) * 4) = hres[t];
            }
        }
        __syncthreads();   // h2s ready

        // === L3: k-partial = h2-slice @ W3-slice -> global kpart[m] (bf16, sc1) ===
        {
            f32x4 a3 = {0.f, 0.f, 0.f, 0.f};
#pragma unroll
            for (int ktl = 0; ktl < 2; ++ktl) {
                bf16x8 hf = *(const bf16x8*)(h2s + (ktl * 4 + rt) * 512 + lane * 8);
                a3 = MFMA(w3f[ktl], hf, a3);
            }
            u16x4 o;
#pragma unroll
            for (int i = 0; i < 4; ++i) o[i] = f2bfu(a3[i]);
            STOREC8(kpu + m * 2048 + row * 32 + nh * 16 + rb4, BC2(o));
        }
        group_sync(&cnt[1], 8u * (unsigned)(e + 1));   // kparts ready group-wide

        // === RK4 combine (replicated; kpart read from MALL via sc1) ===
        {
            i32x2 kq[8];
#pragma unroll
            for (int mm = 0; mm < 8; ++mm)
                LOADC2(kq[mm], kpu + mm * 2048 + rowc * 32 + db);
            asm volatile("s_waitcnt vmcnt(0)" ::: "memory");
            SBAR();
            float kv[4] = {b3v.x, b3v.y, b3v.z, b3v.w};
#pragma unroll
            for (int mm = 0; mm < 8; ++mm) {
                u16x4 q = BCU(kq[mm]);
#pragma unroll
                for (int i = 0; i < 4; ++i) kv[i] += bfu2f(q[i]);
            }
            u16x4 xo;
#pragma unroll
            for (int i = 0; i < 4; ++i) {
                float xe;
                if (s == 0)      { acck[i] = kv[i];          xe = th[i] + 0.5f * dt * kv[i]; }
                else if (s == 1) { acck[i] += 2.f * kv[i];   xe = th[i] + 0.5f * dt * kv[i]; }
                else if (s == 2) { acck[i] += 2.f * kv[i];   xe = th[i] + dt * kv[i]; }
                else             { th[i] += (dt / 6.f) * (acck[i] + kv[i]); xe = th[i]; }
                xo[i] = f2bfu(xe);
            }
            *(u16x4*)(als + (db >> 3) * 512 + rowc * 8 + (db & 7)) = xo;
        }
        __syncthreads();   // x ready for next eval
    }

    if (m == 0) {
        float4 o; o.x = th[0]; o.y = th[1]; o.z = th[2]; o.w = th[3];
        *(float4*)(out + (size_t)(row0 + rowc) * 32 + db) = o;
    }
}

extern "C" void kernel_launch(void* const* d_in, const int* in_sizes, int n_in,
                              void* d_out, int out_size, void* d_ws, size_t ws_size,
                              hipStream_t stream) {
    const float* theta0 = (const float*)d_in[0];
    const float* ctx    = (const float*)d_in[1];
    const float* W1     = (const float*)d_in[2];
    const float* b1     = (const float*)d_in[3];
    const float* W2     = (const float*)d_in[4];
    const float* b2     = (const float*)d_in[5];
    const float* W3     = (const float*)d_in[6];
    const float* b3     = (const float*)d_in[7];
    const int*   nst    = (const int*)d_in[8];
    float* out = (float*)d_out;
    char*  ws  = (char*)d_ws;

    zero_cnt<<<8, 256, 0, stream>>>((unsigned*)(ws + CNTOFF));
    pack_members<<<8 * 173, 64, 0, stream>>>(W1, W2, W3, b1, b2, b3, (unsigned short*)ws);
    ccnf_main<<<NBLK, THREADS, 0, stream>>>(theta0, ctx, ws, nst, out);
}

// Round 19
// 378.004 us; speedup vs baseline: 1.0972x; 1.0972x over previous
//
#include <hip/hip_runtime.h>
#include <hip/hip_bf16.h>

#define THREADS 512
#define NBLK 256
#define NGRP 32
#define GROWS 64
#define IMGU (173*512)                       // ushorts per member image (173 KB)
#define H1OFF  (8*IMGU*2)                    // 1,417,216 B
#define H1BUF  65536                         // one h1 buffer (64 frags)
#define H1GRP  (2*H1BUF)                     // double-buffered per group
#define KPOFF  (H1OFF + (size_t)NGRP*H1GRP)  // + 4 MB
#define KPBUF  32768                         // one kpart buffer (8 members x [64][32] bf16)
#define KPGRP  (2*KPBUF)
#define CNTOFF (KPOFF + (size_t)NGRP*KPGRP)  // + 2 MB; 32 groups x 256 B flag lines

typedef float f32x4 __attribute__((ext_vector_type(4)));
typedef int   i32x2 __attribute__((ext_vector_type(2)));
typedef __bf16 bf16x8 __attribute__((ext_vector_type(8)));
typedef unsigned short u16x4 __attribute__((ext_vector_type(4)));

static __device__ __forceinline__ unsigned short f2bfu(float f) {
    __hip_bfloat16 h = __float2bfloat16(f);
    unsigned short u; __builtin_memcpy(&u, &h, 2); return u;
}
static __device__ __forceinline__ float bfu2f(unsigned short u) {
    unsigned int x = ((unsigned int)u) << 16;
    float f; __builtin_memcpy(&f, &x, 4); return f;
}

#define MFMA(a, b, c) __builtin_amdgcn_mfma_f32_16x16x32_bf16((a), (b), (c), 0, 0, 0)
#define BC(x)  __builtin_bit_cast(bf16x8, (x))
#define BC2(x) __builtin_bit_cast(i32x2, (x))
#define BCU(x) __builtin_bit_cast(u16x4, (x))

// agent-scope (sc1) communication ops: write-through to MALL / read MALL, bypass L1+L2.
#define LOADG(dst, addr) \
    asm volatile("global_load_dwordx4 %0, %1, off sc1" : "=v"(dst) : "v"(addr))
#define LOADC2(dst, addr) \
    asm volatile("global_load_dwordx2 %0, %1, off sc1" : "=v"(dst) : "v"(addr))
#define STOREC8(addr, val) \
    asm volatile("global_store_dwordx2 %0, %1, off sc1" :: "v"(addr), "v"(val) : "memory")
#define SBAR() __builtin_amdgcn_sched_barrier(0)

__global__ void zero_cnt(unsigned* c) { c[blockIdx.x * 256 + threadIdx.x] = 0u; }

// Per-member weight image: 128 W2 frags | 32 W1c frags | 8 W1a frags | 4 W3 frags | vec block.
// Frag element: lane l, j -> W[k = kt*32 + (l>>4)*8 + j][n = ntg*16 + (l&15)]
__global__ void pack_members(const float* __restrict__ W1, const float* __restrict__ W2,
                             const float* __restrict__ W3, const float* __restrict__ b1,
                             const float* __restrict__ b2, const float* __restrict__ b3,
                             unsigned short* __restrict__ dst) {
    int b = blockIdx.x, m = b / 173, fi = b % 173, lane = threadIdx.x;
    unsigned short* base = dst + (size_t)m * IMGU;
    if (fi == 172) {   // vec block: w1tA|w1tB|b1A|b1B|b2A|b2B (64 u16 each) + b3 (32 f32)
        unsigned short* vb = base + 172 * 512;
        for (int i = lane; i < 384; i += 64) {
            int region = i >> 6, o = i & 63;
            int cA = m * 64 + o, cB = 512 + m * 64 + o;
            float v = 0.f;
            if (region == 0) v = W1[32 * 1024 + cA];
            else if (region == 1) v = W1[32 * 1024 + cB];
            else if (region == 2) v = b1[cA];
            else if (region == 3) v = b1[cB];
            else if (region == 4) v = b2[cA];
            else                  v = b2[cB];
            vb[i] = f2bfu(v);
        }
        if (lane < 32) ((float*)(vb + 384))[lane] = b3[lane];
        return;
    }
    const float* W; int kbase, n, N;
    if (fi < 128) {        // W2 slice frags: idx = kt*8 + ntl
        int kt = fi >> 3, ntl = fi & 7;
        int ntg = (ntl < 4) ? (m * 4 + ntl) : (32 + m * 4 + (ntl - 4));
        W = W2; N = 1024; kbase = kt * 32; n = ntg * 16 + (lane & 15);
    } else if (fi < 160) { // W1c frags: idx = ktc*8 + ntl (ctx rows 33..160)
        int fj = fi - 128, ktc = fj >> 3, ntl = fj & 7;
        int ntg = (ntl < 4) ? (m * 4 + ntl) : (32 + m * 4 + (ntl - 4));
        W = W1 + 33 * 1024; N = 1024; kbase = ktc * 32; n = ntg * 16 + (lane & 15);
    } else if (fi < 168) { // W1a frags: idx = ntl (theta rows 0..31)
        int ntl = fi - 160;
        int ntg = (ntl < 4) ? (m * 4 + ntl) : (32 + m * 4 + (ntl - 4));
        W = W1; N = 1024; kbase = 0; n = ntg * 16 + (lane & 15);
    } else {               // W3 frags: idx = ktl*2 + nt3 (K-slice rows m*64..)
        int fj = fi - 168, ktl = fj >> 1, nt3 = fj & 1;
        W = W3; N = 32; kbase = m * 64 + ktl * 32; n = nt3 * 16 + (lane & 15);
    }
    kbase += (lane >> 4) * 8;
    union { unsigned short s[8]; int4 v; } u;
#pragma unroll
    for (int j = 0; j < 8; j++) u.s[j] = f2bfu(W[(size_t)(kbase + j) * N + n]);
    *reinterpret_cast<int4*>(base + (size_t)fi * 512 + lane * 8) = u.v;
}

// Wave-level wait: poll 8 monotonic flags (one 32B sector) with sc1 loads until all >= tgt.
// No barriers: every wave self-releases the moment the flags are set.
static __device__ __forceinline__ void wait8(const unsigned* f8, unsigned tgt) {
    const unsigned* fp = f8 + (threadIdx.x & 7);
    unsigned v; int gd = 0;
    for (;;) {
        asm volatile("global_load_dword %0, %1, off sc1" : "=v"(v) : "v"(fp));
        asm volatile("s_waitcnt vmcnt(0)" ::: "memory");
        if (__all((int)(v >= tgt))) break;
        __builtin_amdgcn_s_sleep(1);
        if (++gd > (1 << 22)) break;   // safety valve: terminate, never hang
    }
    __builtin_amdgcn_sched_barrier(0);
}

__global__ __launch_bounds__(THREADS, 2)
void ccnf_main(const float* __restrict__ theta0,
               const float* __restrict__ ctx,
               char* __restrict__ wsb,
               const int* __restrict__ nsteps_p,
               float* __restrict__ out)
{
    // LDS: W2 128K | cxt1 16K | h2 8K | x 4K = 156 KB (1 block/CU)
    __shared__ __align__(16) unsigned short w2s[128 * 512];
    __shared__ __align__(16) unsigned short cxts[32 * 64 * 4];  // [z4][row][4] (conflict-free)
    __shared__ __align__(16) unsigned short h2s[8 * 512];       // frag(ktl*4+rt)
    __shared__ __align__(16) unsigned short als[2048];          // x frags [d>>3][row][d&7]

    const int tid = threadIdx.x;
    const int lane = tid & 63, wv = tid >> 6;
    const int rt = wv & 3, nh = wv >> 2;            // wave -> (rowtile, n-half)
    const int r16 = lane & 15, wq = lane >> 4, rb4 = wq * 4;
    const int row = rt * 16 + r16;
    const int g = blockIdx.x & 31, m = blockIdx.x >> 5;
    const int row0 = g * GROWS;

    const unsigned short* img = (const unsigned short*)wsb + (size_t)m * IMGU;
    char* h1base = wsb + H1OFF + (size_t)g * H1GRP;
    char* kpbase = wsb + KPOFF + (size_t)g * KPGRP;
    unsigned* flg = (unsigned*)(wsb + CNTOFF) + g * 64;   // [0..7]=flgH, [8..15]=flgK

    // ---- resident VGPR constants ----
    bf16x8 w1aA[2], w1aB[2], w3f[2];
    u16x4 w1tA[2], w1tB[2], b1A[2], b1B[2], b2A[2], b2B[2];
#pragma unroll
    for (int k = 0; k < 2; ++k) {
        w1aA[k] = *(const bf16x8*)(img + (160 + 2 * nh + k) * 512 + lane * 8);
        w1aB[k] = *(const bf16x8*)(img + (164 + 2 * nh + k) * 512 + lane * 8);
        w3f[k]  = *(const bf16x8*)(img + (168 + k * 2 + nh) * 512 + lane * 8);
        int cl = (2 * nh + k) * 16 + rb4;
        const unsigned short* vu = img + 172 * 512;
        w1tA[k] = *(const u16x4*)(vu + cl);       w1tB[k] = *(const u16x4*)(vu + 64 + cl);
        b1A[k]  = *(const u16x4*)(vu + 128 + cl); b1B[k]  = *(const u16x4*)(vu + 192 + cl);
        b2A[k]  = *(const u16x4*)(vu + 256 + cl); b2B[k]  = *(const u16x4*)(vu + 320 + cl);
    }
    const int rowc = tid >> 3, db = (tid & 7) * 4;
    const float4 b3v = *(const float4*)((const float*)(img + 172 * 512 + 384) + db);

    // ---- prologue: W1c -> LDS (transient), ctx staging, theta ----
#pragma unroll
    for (int q = 0; q < 4; ++q) {   // 32 W1c frags -> w2s[0..32)
        int idx = wv * 4 + q;
        __builtin_amdgcn_global_load_lds(
            (const __attribute__((address_space(1))) void*)((const char*)img + (size_t)(128 + idx) * 1024 + lane * 16),
            (__attribute__((address_space(3))) void*)(w2s + idx * 512), 16, 0, 0);
    }
    {   // ctx [64 rows][128] fp32 -> staging frags at w2s[32*512..]
        const float* cp = ctx + (size_t)(row0 + rowc) * 128 + (tid & 7) * 16;
        float4 v0 = ((const float4*)cp)[0], v1 = ((const float4*)cp)[1];
        float4 v2 = ((const float4*)cp)[2], v3 = ((const float4*)cp)[3];
        int c0 = (tid & 7) * 16;
        unsigned short* sb = w2s + 16384 + (c0 >> 5) * 2048 + ((c0 & 31) >> 3) * 512 + rowc * 8;
        u16x4 o;
        o[0]=f2bfu(v0.x); o[1]=f2bfu(v0.y); o[2]=f2bfu(v0.z); o[3]=f2bfu(v0.w); *(u16x4*)(sb) = o;
        o[0]=f2bfu(v1.x); o[1]=f2bfu(v1.y); o[2]=f2bfu(v1.z); o[3]=f2bfu(v1.w); *(u16x4*)(sb + 4) = o;
        o[0]=f2bfu(v2.x); o[1]=f2bfu(v2.y); o[2]=f2bfu(v2.z); o[3]=f2bfu(v2.w); *(u16x4*)(sb + 512) = o;
        o[0]=f2bfu(v3.x); o[1]=f2bfu(v3.y); o[2]=f2bfu(v3.z); o[3]=f2bfu(v3.w); *(u16x4*)(sb + 516) = o;
    }
    float th[4], acck[4];
    {
        float4 t0 = *(const float4*)(theta0 + (size_t)(row0 + rowc) * 32 + db);
        th[0]=t0.x; th[1]=t0.y; th[2]=t0.z; th[3]=t0.w;
        acck[0]=acck[1]=acck[2]=acck[3]=0.f;
        u16x4 xo; xo[0]=f2bfu(t0.x); xo[1]=f2bfu(t0.y); xo[2]=f2bfu(t0.z); xo[3]=f2bfu(t0.w);
        *(u16x4*)(als + (db >> 3) * 512 + rowc * 8 + (db & 7)) = xo;
    }
    const int nst = nsteps_p[0];
    const float dt = 1.0f / (float)nst;
    __syncthreads();

    // ---- cxt1 = ctx @ W1c-slice; store z4-major [z4][row][4] ----
#pragma unroll
    for (int ab = 0; ab < 2; ++ab)
#pragma unroll
        for (int k = 0; k < 2; ++k) {
            int ntl = ab * 4 + 2 * nh + k;
            f32x4 a = {0.f, 0.f, 0.f, 0.f};
#pragma unroll
            for (int ktc = 0; ktc < 4; ++ktc) {
                bf16x8 cf = *(const bf16x8*)(w2s + 16384 + ktc * 2048 + wq * 512 + row * 8);
                bf16x8 wf = *(const bf16x8*)(w2s + (ktc * 8 + ntl) * 512 + lane * 8);
                a = MFMA(wf, cf, a);
            }
            u16x4 o;
#pragma unroll
            for (int i = 0; i < 4; ++i) o[i] = f2bfu(a[i]);
            int z4 = ab * 16 + (2 * nh + k) * 4 + wq;
            *(u16x4*)(cxts + (z4 * 64 + row) * 4) = o;
        }
    __syncthreads();   // W1c/ctx staging consumed; w2s free

    // ---- W2 slice -> LDS (resident) ----
#pragma unroll
    for (int q = 0; q < 16; ++q) {
        int idx = wv * 16 + q;
        __builtin_amdgcn_global_load_lds(
            (const __attribute__((address_space(1))) void*)((const char*)img + (size_t)idx * 1024 + lane * 16),
            (__attribute__((address_space(3))) void*)(w2s + idx * 512), 16, 0, 0);
    }
    __syncthreads();   // W2 resident before first L2

    // ---- main loop: 4*nst evals; producer-flag sync, double-buffered h1/kpart ----
    const int ne = 4 * nst;
    for (int e = 0; e < ne; ++e) {
        const int s = e & 3;
        const float tt = (float)(e >> 2) * dt + ((s == 0) ? 0.f : (s == 3) ? dt : 0.5f * dt);
        const unsigned tgt = (unsigned)(e + 1);
        unsigned short* h1e = (unsigned short*)(h1base + (e & 1) * H1BUF);
        unsigned short* kpe = (unsigned short*)(kpbase + (e & 1) * KPBUF);
        const char* h1lane = (const char*)h1e + lane * 16;

        // === L1: z-slice = x@W1a + cxt1 + b1 + t*w1t; GLU -> h1e frag(2m+nh, rt), sc1 ===
        {
            bf16x8 xf = *(const bf16x8*)(als + wq * 512 + row * 8);
            unsigned short* fb = h1e + ((2 * m + nh) * 4 + rt) * 512;
#pragma unroll
            for (int k = 0; k < 2; ++k) {
                f32x4 z = {0.f, 0.f, 0.f, 0.f};
                f32x4 zA = MFMA(w1aA[k], xf, z);
                f32x4 zB = MFMA(w1aB[k], xf, z);
                int zA4 = (2 * nh + k) * 4 + wq, zB4 = 16 + zA4;
                u16x4 cA = *(const u16x4*)(cxts + (zA4 * 64 + row) * 4);
                u16x4 cB = *(const u16x4*)(cxts + (zB4 * 64 + row) * 4);
                u16x4 o;
#pragma unroll
                for (int i = 0; i < 4; ++i) {
                    float va = zA[i] + bfu2f(cA[i]) + bfu2f(b1A[k][i]) + tt * bfu2f(w1tA[k][i]);
                    float vb = zB[i] + bfu2f(cB[i]) + bfu2f(b1B[k][i]) + tt * bfu2f(w1tB[k][i]);
                    o[i] = f2bfu(va * (1.f / (1.f + __expf(-vb))));
                }
                STOREC8(fb + (k * 2 + (wq >> 1)) * 128 + r16 * 8 + (wq & 1) * 4, BC2(o));
            }
        }
        __syncthreads();   // drains all waves' h1 sc1 stores to MALL
        if (tid == 0)
            asm volatile("global_store_dword %0, %1, off sc1" :: "v"(flg + m), "v"(tgt) : "memory");
        wait8(flg, tgt);   // all members' h1 published

        // === L2: 16 h1 B-frags (MALL, 8-deep pipeline, member-rotated), A = W2 (LDS) ===
        {
            f32x4 acc[4];
#pragma unroll
            for (int p = 0; p < 4; ++p) { f32x4 z = {0.f,0.f,0.f,0.f}; acc[p] = z; }
            f32x4 gb[8];
#pragma unroll
            for (int q = 0; q < 8; ++q) {
                const int qi = (q + 2 * m) & 15;
                LOADG(gb[q], h1lane + (qi * 4 + rt) * 1024);
            }
#pragma unroll
            for (int j = 0; j < 16; ++j) {
                if (j <= 8)       asm volatile("s_waitcnt vmcnt(7)" ::: "memory");
                else if (j == 9)  asm volatile("s_waitcnt vmcnt(6)" ::: "memory");
                else if (j == 10) asm volatile("s_waitcnt vmcnt(5)" ::: "memory");
                else if (j == 11) asm volatile("s_waitcnt vmcnt(4)" ::: "memory");
                else if (j == 12) asm volatile("s_waitcnt vmcnt(3)" ::: "memory");
                else if (j == 13) asm volatile("s_waitcnt vmcnt(2)" ::: "memory");
                else if (j == 14) asm volatile("s_waitcnt vmcnt(1)" ::: "memory");
                else              asm volatile("s_waitcnt vmcnt(0)" ::: "memory");
                SBAR();
                const int kt = (j + 2 * m) & 15;
                bf16x8 hf = BC(gb[j & 7]);
                acc[0] = MFMA(*(const bf16x8*)(w2s + (kt * 8 + 2 * nh + 0) * 512 + lane * 8), hf, acc[0]);
                acc[1] = MFMA(*(const bf16x8*)(w2s + (kt * 8 + 2 * nh + 1) * 512 + lane * 8), hf, acc[1]);
                acc[2] = MFMA(*(const bf16x8*)(w2s + (kt * 8 + 4 + 2 * nh + 0) * 512 + lane * 8), hf, acc[2]);
                acc[3] = MFMA(*(const bf16x8*)(w2s + (kt * 8 + 4 + 2 * nh + 1) * 512 + lane * 8), hf, acc[3]);
                SBAR();
                if (j < 8) {
                    const int qi = (j + 8 + 2 * m) & 15;
                    LOADG(gb[j & 7], h1lane + (qi * 4 + rt) * 1024);
                }
            }
            // GLU(+b2) -> h2s frag(nh*4+rt) (LDS, block-local)
#pragma unroll
            for (int k = 0; k < 2; ++k) {
                u16x4 o;
#pragma unroll
                for (int i = 0; i < 4; ++i) {
                    float va = acc[k][i] + bfu2f(b2A[k][i]);
                    float vb = acc[2 + k][i] + bfu2f(b2B[k][i]);
                    o[i] = f2bfu(va * (1.f / (1.f + __expf(-vb))));
                }
                *(u16x4*)(h2s + (nh * 4 + rt) * 512 + (k * 2 + (wq >> 1)) * 128 + r16 * 8 + (wq & 1) * 4) = o;
            }
        }
        __syncthreads();   // h2s ready

        // === L3: k-partial = h2-slice @ W3-slice -> kpe[m] (bf16, sc1) ===
        {
            f32x4 a3 = {0.f, 0.f, 0.f, 0.f};
#pragma unroll
            for (int ktl = 0; ktl < 2; ++ktl) {
                bf16x8 hf = *(const bf16x8*)(h2s + (ktl * 4 + rt) * 512 + lane * 8);
                a3 = MFMA(w3f[ktl], hf, a3);
            }
            u16x4 o;
#pragma unroll
            for (int i = 0; i < 4; ++i) o[i] = f2bfu(a3[i]);
            STOREC8(kpe + m * 2048 + row * 32 + nh * 16 + rb4, BC2(o));
        }
        __syncthreads();   // drains kpart sc1 stores
        if (tid == 0)
            asm volatile("global_store_dword %0, %1, off sc1" :: "v"(flg + 8 + m), "v"(tgt) : "memory");
        wait8(flg + 8, tgt);   // all members' kparts published

        // === RK4 combine (replicated; kpart read from MALL via sc1) ===
        {
            i32x2 kq[8];
#pragma unroll
            for (int mm = 0; mm < 8; ++mm)
                LOADC2(kq[mm], kpe + mm * 2048 + rowc * 32 + db);
            asm volatile("s_waitcnt vmcnt(0)" ::: "memory");
            SBAR();
            float kv[4] = {b3v.x, b3v.y, b3v.z, b3v.w};
#pragma unroll
            for (int mm = 0; mm < 8; ++mm) {
                u16x4 q = BCU(kq[mm]);
#pragma unroll
                for (int i = 0; i < 4; ++i) kv[i] += bfu2f(q[i]);
            }
            u16x4 xo;
#pragma unroll
            for (int i = 0; i < 4; ++i) {
                float xe;
                if (s == 0)      { acck[i] = kv[i];          xe = th[i] + 0.5f * dt * kv[i]; }
                else if (s == 1) { acck[i] += 2.f * kv[i];   xe = th[i] + 0.5f * dt * kv[i]; }
                else if (s == 2) { acck[i] += 2.f * kv[i];   xe = th[i] + dt * kv[i]; }
                else             { th[i] += (dt / 6.f) * (acck[i] + kv[i]); xe = th[i]; }
                xo[i] = f2bfu(xe);
            }
            *(u16x4*)(als + (db >> 3) * 512 + rowc * 8 + (db & 7)) = xo;
        }
        __syncthreads();   // x ready for next eval
    }

    if (m == 0) {
        float4 o; o.x = th[0]; o.y = th[1]; o.z = th[2]; o.w = th[3];
        *(float4*)(out + (size_t)(row0 + rowc) * 32 + db) = o;
    }
}

extern "C" void kernel_launch(void* const* d_in, const int* in_sizes, int n_in,
                              void* d_out, int out_size, void* d_ws, size_t ws_size,
                              hipStream_t stream) {
    const float* theta0 = (const float*)d_in[0];
    const float* ctx    = (const float*)d_in[1];
    const float* W1     = (const float*)d_in[2];
    const float* b1     = (const float*)d_in[3];
    const float* W2     = (const float*)d_in[4];
    const float* b2     = (const float*)d_in[5];
    const float* W3     = (const float*)d_in[6];
    const float* b3     = (const float*)d_in[7];
    const int*   nst    = (const int*)d_in[8];
    float* out = (float*)d_out;
    char*  ws  = (char*)d_ws;

    zero_cnt<<<8, 256, 0, stream>>>((unsigned*)(ws + CNTOFF));
    pack_members<<<8 * 173, 64, 0, stream>>>(W1, W2, W3, b1, b2, b3, (unsigned short*)ws);
    ccnf_main<<<NBLK, THREADS, 0, stream>>>(theta0, ctx, ws, nst, out);
}